// Round 6
// baseline (916.132 us; speedup 1.0000x reference)
//
#include <hip/hip_runtime.h>
#include <hip/hip_bf16.h>
#include <math.h>

typedef __hip_bfloat16 bf16;
using f32x4  = __attribute__((ext_vector_type(4))) float;
using short8 = __attribute__((ext_vector_type(8))) short;

#define DEV __device__ __forceinline__

static constexpr int BS = 4, L = 4096, D = 1024;
static constexpr int M  = BS * L;              // 16384 rows
static constexpr int NCH = 128;                // scan chunks
static constexpr int CLEN = L / NCH;           // 32 steps per chunk
static constexpr size_t SZ1 = (size_t)M * D;   // elems of one [M,1024]

// ---------------- workspace layout (bytes), total = 224 MiB ----------
static constexpr size_t OFF_XN    = 0;                    // bf16 [M,1024] 32MB (xn; scan scratch; xn2)
static constexpr size_t OFF_GATES = 33554432;             // bf16 4x[M,1024] 128MB (later ff [M,4096])
static constexpr size_t OFF_XR    = 167772160;            // bf16 [M,1024] 32MB residual
static constexpr size_t OFF_WG    = 201326592;            // bf16 [4096,1024] gate weights B^T (8MB)
static constexpr size_t OFF_WF    = 209715200;            // bf16 [8192,1024] ffn B^T interleaved (16MB)
static constexpr size_t OFF_WO    = 226492416;            // bf16 [1024,4096] W_out B^T (8MB) -> end 224MiB
// scan scratch aliases XN region (xn dead between gemm<0> and rmsnorm2):
static constexpr size_t OFF_SCA   = OFF_XN;               // f32 [128,4096] 2MB
static constexpr size_t OFF_SCB   = OFF_XN + 2097152;     // f32 [128,4096] 2MB
static constexpr size_t OFF_SCH   = OFF_XN + 4194304;     // f32 [128,4096] 2MB

DEV void mfma16x16x32(f32x4& d, short8 a, short8 b) {
  asm("v_mfma_f32_16x16x32_bf16 %0, %1, %2, %0" : "+v"(d) : "v"(a), "v"(b));
}

DEV void async16(const void* g, void* l) {
  __builtin_amdgcn_global_load_lds(
      (__attribute__((address_space(1))) unsigned int*)g,
      (__attribute__((address_space(3))) unsigned int*)l, 16, 0, 0);
}

DEV float sigm(float z) { return 1.0f / (1.0f + __expf(-z)); }
DEV float b2f(short s) { return __uint_as_float(((unsigned)(unsigned short)s) << 16); }
DEV short f2s(float f) { union { bf16 h; short s; } c; c.h = __float2bfloat16(f); return c.s; }

// in [K,N] f32 row-major -> out [N,K] bf16 (B^T layout). grid (N/32, K/32), block (32,8)
__global__ void transpose_cvt(const float* __restrict__ in, bf16* __restrict__ out, int K, int N) {
  __shared__ float t[32][33];
  const int n0 = blockIdx.x * 32, k0 = blockIdx.y * 32;
  const int tx = threadIdx.x, ty = threadIdx.y;
#pragma unroll
  for (int j = 0; j < 4; ++j)
    t[ty + 8 * j][tx] = in[(size_t)(k0 + ty + 8 * j) * N + n0 + tx];
  __syncthreads();
#pragma unroll
  for (int j = 0; j < 4; ++j)
    out[(size_t)(n0 + ty + 8 * j) * K + k0 + tx] = __float2bfloat16(t[tx][ty + 8 * j]);
}

// ffn B^T with 32-col interleave: row n: q=n&63, J=(n>>6)*32+(q&31), src = q<32 ? W_fc : W_act
// grid (8192/32, 1024/32), block (32,8)
__global__ void transpose_ffn(const float* __restrict__ Wfc, const float* __restrict__ Wact,
                              bf16* __restrict__ out) {
  __shared__ float t[32][33];
  const int n0 = blockIdx.x * 32;        // output row block (uniform fc/act half)
  const int k0 = blockIdx.y * 32;
  const int Jb = (n0 >> 6) * 32;
  const float* src = ((n0 >> 5) & 1) ? Wact : Wfc;
  const int tx = threadIdx.x, ty = threadIdx.y;
#pragma unroll
  for (int j = 0; j < 4; ++j)
    t[ty + 8 * j][tx] = src[(size_t)(k0 + ty + 8 * j) * 4096 + Jb + tx];
  __syncthreads();
#pragma unroll
  for (int j = 0; j < 4; ++j)
    out[(size_t)(n0 + ty + 8 * j) * 1024 + k0 + tx] = __float2bfloat16(t[tx][ty + 8 * j]);
}

// ---------------- rmsnorm f32-in -> bf16 out, one row per block ----------------
__global__ __launch_bounds__(256)
void rmsnorm_f32in(const float* __restrict__ x, const float* __restrict__ g, bf16* __restrict__ out) {
  __shared__ float red[4];
  const size_t row = blockIdx.x;
  const int t = threadIdx.x;
  const float4 v = ((const float4*)(x + row * D))[t];
  float ss = v.x * v.x + v.y * v.y + v.z * v.z + v.w * v.w;
#pragma unroll
  for (int o = 32; o > 0; o >>= 1) ss += __shfl_down(ss, o);
  if ((t & 63) == 0) red[t >> 6] = ss;
  __syncthreads();
  const float tot = red[0] + red[1] + red[2] + red[3];
  const float sc = rsqrtf(tot * (1.0f / D) + 1e-6f);
  const float4 gg = ((const float4*)g)[t];
  ushort4 o;
  o.x = (unsigned short)f2s(v.x * sc * gg.x);
  o.y = (unsigned short)f2s(v.y * sc * gg.y);
  o.z = (unsigned short)f2s(v.z * sc * gg.z);
  o.w = (unsigned short)f2s(v.w * sc * gg.w);
  ((ushort4*)(out + row * D))[t] = o;
}

// ---------------- rmsnorm bf16-in -> bf16 out ----------------
__global__ __launch_bounds__(256)
void rmsnorm_b16in(const bf16* __restrict__ x, const float* __restrict__ g, bf16* __restrict__ out) {
  __shared__ float red[4];
  const size_t row = blockIdx.x;
  const int t = threadIdx.x;
  const ushort4 v = ((const ushort4*)(x + row * D))[t];
  const float a0 = b2f((short)v.x), a1 = b2f((short)v.y), a2 = b2f((short)v.z), a3 = b2f((short)v.w);
  float ss = a0 * a0 + a1 * a1 + a2 * a2 + a3 * a3;
#pragma unroll
  for (int o = 32; o > 0; o >>= 1) ss += __shfl_down(ss, o);
  if ((t & 63) == 0) red[t >> 6] = ss;
  __syncthreads();
  const float tot = red[0] + red[1] + red[2] + red[3];
  const float sc = rsqrtf(tot * (1.0f / D) + 1e-6f);
  const float4 gg = ((const float4*)g)[t];
  ushort4 o;
  o.x = (unsigned short)f2s(a0 * sc * gg.x);
  o.y = (unsigned short)f2s(a1 * sc * gg.y);
  o.z = (unsigned short)f2s(a2 * sc * gg.z);
  o.w = (unsigned short)f2s(a3 * sc * gg.w);
  ((ushort4*)(out + row * D))[t] = o;
}

// ---------------- bf16 MFMA GEMM: C[M,N] = A[M,K] @ Bt[N,K]^T ----------------
// m97-proven structure: 128x128 tile, BK=64, 4 waves (2x2), each wave 64x64
// (4x4 frags of 16x16x32). LINEAR LDS (no swizzle), global_load_lds width 16,
// 2 barriers per K-step.
// EPI 0: gates (sigmoid/tanh -> 4 bf16 bufs)   out0 = bf16* gates base
// EPI 1: swiglu (u*silu(v), 32-col interleave) out0 = bf16* ff
// EPI 2: out (+bias +resid -> f32 d_out)       out0 = float* d_out, residb=xr
template <int EPI>
__global__ __launch_bounds__(256)
void gemm_bt(const bf16* __restrict__ A, const bf16* __restrict__ Bt, int K,
             const float* __restrict__ ba, const float* __restrict__ bb,
             const float* __restrict__ bc, const float* __restrict__ bd,
             const bf16* __restrict__ residb, void* __restrict__ out0) {
  __shared__ bf16 sA[128 * 64];
  __shared__ bf16 sB[128 * 64];
  const int tid = threadIdx.x;
  const int lane = tid & 63;
  const int w = tid >> 6;
  const int wr = w >> 1, wc = w & 1;
  const int m0 = blockIdx.y * 128, n0 = blockIdx.x * 128;
  const int l15 = lane & 15, lg = lane >> 4;

  f32x4 acc[4][4] = {};

  for (int kt = 0; kt < K; kt += 64) {
    __syncthreads();                              // LDS reuse: prior reads drained
#pragma unroll
    for (int r = 0; r < 4; ++r) {
      const int lin = (r * 256 + tid) * 8;        // element index in 128x64 tile
      const int row = lin >> 6;
      const int col = lin & 63;                   // element col (16B-aligned group)
      async16(A  + (size_t)(m0 + row) * K + kt + col, (char*)sA + lin * 2);
      async16(Bt + (size_t)(n0 + row) * K + kt + col, (char*)sB + lin * 2);
    }
    __syncthreads();                              // compiler drains vmcnt(0) before barrier
#pragma unroll
    for (int kk = 0; kk < 2; ++kk) {
      short8 af[4], bfr[4];
      const int cb = kk * 64 + lg * 16;           // byte col within 128B row
#pragma unroll
      for (int i = 0; i < 4; ++i) {
        const int row = wr * 64 + i * 16 + l15;
        af[i] = *(const short8*)((const char*)sA + row * 128 + cb);
      }
#pragma unroll
      for (int j = 0; j < 4; ++j) {
        const int row = wc * 64 + j * 16 + l15;
        bfr[j] = *(const short8*)((const char*)sB + row * 128 + cb);
      }
#pragma unroll
      for (int i = 0; i < 4; ++i)
#pragma unroll
        for (int j = 0; j < 4; ++j)
          mfma16x16x32(acc[i][j], af[i], bfr[j]);
    }
  }
  // MFMA(asm, opaque to compiler) -> VALU read hazard fence, order-pinned (rule #18)
  __builtin_amdgcn_sched_barrier(0);
  asm volatile("s_nop 7\n\ts_nop 7\n\ts_nop 7" ::);
  __builtin_amdgcn_sched_barrier(0);

  if constexpr (EPI == 0) {
    bf16* gbuf = (bf16*)out0;
#pragma unroll
    for (int i = 0; i < 4; ++i) {
#pragma unroll
      for (int j = 0; j < 4; ++j) {
        const int col = n0 + wc * 64 + j * 16 + l15;
        const int gate = col >> 10;               // wave-uniform per tile
        const int c1 = col & 1023;
        const float* bp = (gate == 0) ? ba : (gate == 1) ? bb : (gate == 2) ? bc : bd;
        bf16* dst = gbuf + (size_t)gate * SZ1;
        const float bz = bp[c1];
#pragma unroll
        for (int r = 0; r < 4; ++r) {
          const int row = m0 + wr * 64 + i * 16 + lg * 4 + r;
          const float z = acc[i][j][r] + bz;
          const float v = (gate == 1) ? tanhf(z) : sigm(z);
          dst[(size_t)row * 1024 + c1] = __float2bfloat16(v);
        }
      }
    }
  } else if constexpr (EPI == 1) {
    bf16* ff = (bf16*)out0;
    const int Jbase = (n0 + wc * 64) >> 1;        // = group*32
#pragma unroll
    for (int i = 0; i < 4; ++i) {
#pragma unroll
      for (int j = 0; j < 2; ++j) {
        const int J = Jbase + j * 16 + l15;       // true ffn column in [0,4096)
        const float bu = ba[J], bv = bb[J];       // b_fc, b_act
#pragma unroll
        for (int r = 0; r < 4; ++r) {
          const int row = m0 + wr * 64 + i * 16 + lg * 4 + r;
          const float u = acc[i][j][r] + bu;
          const float v = acc[i][j + 2][r] + bv;
          const float s = v * sigm(v);            // silu
          ff[(size_t)row * 4096 + J] = __float2bfloat16(u * s);
        }
      }
    }
  } else {
    float* outp = (float*)out0;                   // f32 output (reference dtype)
#pragma unroll
    for (int i = 0; i < 4; ++i) {
#pragma unroll
      for (int j = 0; j < 4; ++j) {
        const int col = n0 + wc * 64 + j * 16 + l15;
        const float bz = ba[col];                 // b_out
#pragma unroll
        for (int r = 0; r < 4; ++r) {
          const int row = m0 + wr * 64 + i * 16 + lg * 4 + r;
          const size_t idx = (size_t)row * 1024 + col;
          outp[idx] = acc[i][j][r] + bz + __bfloat162float(residb[idx]);
        }
      }
    }
  }
}

// ---------------- chunked LSTM scan ----------------
// h_t = f_t*h_{t-1} + i_t with h_0 = hidden  (== scan from 0 + hidden*cumprod(f))
// Each thread owns 8 consecutive channels of one chunk (short8 loads).
__global__ __launch_bounds__(256)
void scan_A(const bf16* __restrict__ f, const bf16* __restrict__ ti, const bf16* __restrict__ si,
            float* __restrict__ Ac, float* __restrict__ Bc) {
  const int gi = blockIdx.x * 256 + threadIdx.x;   // [0, NCH*512)
  const int c = gi >> 9, rb = gi & 511;
  const int b = rb >> 7, d0 = (rb & 127) << 3;
  size_t idx = ((size_t)b * L + (size_t)c * CLEN) * D + d0;
  float ap[8], acc[8];
#pragma unroll
  for (int j = 0; j < 8; ++j) { ap[j] = 1.0f; acc[j] = 0.0f; }
#pragma unroll 4
  for (int t = 0; t < CLEN; ++t, idx += D) {
    const short8 f8 = *(const short8*)(f + idx);
    const short8 t8 = *(const short8*)(ti + idx);
    const short8 s8 = *(const short8*)(si + idx);
#pragma unroll
    for (int j = 0; j < 8; ++j) {
      const float fv = b2f(f8[j]);
      const float iv = b2f(t8[j]) * b2f(s8[j]);
      acc[j] = fmaf(fv, acc[j], iv);
      ap[j] *= fv;
    }
  }
  const int o = c * 4096 + rb * 8;
#pragma unroll
  for (int j = 0; j < 8; ++j) { Ac[o + j] = ap[j]; Bc[o + j] = acc[j]; }
}

__global__ __launch_bounds__(256)
void scan_Bk(const float* __restrict__ Ac, const float* __restrict__ Bc,
             const float* __restrict__ hidden, float* __restrict__ Hin) {
  const int r = blockIdx.x * 256 + threadIdx.x;    // [0,4096): b*1024+d
  float h = hidden[r];
  for (int c = 0; c < NCH; ++c) {
    const int idx = c * 4096 + r;
    Hin[idx] = h;
    h = fmaf(Ac[idx], h, Bc[idx]);
  }
}

__global__ __launch_bounds__(256)
void scan_C(const bf16* __restrict__ f, const bf16* __restrict__ ti, const bf16* __restrict__ si,
            const bf16* __restrict__ og, const float* __restrict__ x, const float* __restrict__ Hin,
            bf16* __restrict__ xr, float* __restrict__ hlast) {
  const int gi = blockIdx.x * 256 + threadIdx.x;
  const int c = gi >> 9, rb = gi & 511;
  const int b = rb >> 7, d0 = (rb & 127) << 3;
  size_t idx = ((size_t)b * L + (size_t)c * CLEN) * D + d0;
  float h[8];
#pragma unroll
  for (int j = 0; j < 8; ++j) h[j] = Hin[c * 4096 + rb * 8 + j];
#pragma unroll 2
  for (int t = 0; t < CLEN; ++t, idx += D) {
    const short8 f8 = *(const short8*)(f + idx);
    const short8 t8 = *(const short8*)(ti + idx);
    const short8 s8 = *(const short8*)(si + idx);
    const short8 o8 = *(const short8*)(og + idx);
    const float4 xa = *(const float4*)(x + idx);
    const float4 xb = *(const float4*)(x + idx + 4);
    short8 ro;
#pragma unroll
    for (int j = 0; j < 8; ++j) {
      const float fv = b2f(f8[j]);
      const float iv = b2f(t8[j]) * b2f(s8[j]);
      h[j] = fmaf(fv, h[j], iv);
      const float y = tanhf(h[j]) * b2f(o8[j]);
      const float xv = (j < 4) ? ((const float*)&xa)[j] : ((const float*)&xb)[j - 4];
      ro[j] = f2s(xv + y);
    }
    *(short8*)(xr + idx) = ro;
  }
  if (c == NCH - 1) {
#pragma unroll
    for (int j = 0; j < 8; ++j) hlast[rb * 8 + j] = h[j];
  }
}

// ---------------- launcher ----------------
extern "C" void kernel_launch(void* const* d_in, const int* in_sizes, int n_in,
                              void* d_out, int out_size, void* d_ws, size_t ws_size,
                              hipStream_t stream) {
  (void)in_sizes; (void)n_in; (void)out_size; (void)ws_size;
  const float* x      = (const float*)d_in[0];
  const float* hidden = (const float*)d_in[1];
  const float* g_ql   = (const float*)d_in[2];
  const float* g_ffn  = (const float*)d_in[3];
  const float* W_f    = (const float*)d_in[4];
  const float* b_f    = (const float*)d_in[5];
  const float* W_i    = (const float*)d_in[6];
  const float* b_i    = (const float*)d_in[7];
  const float* W_ig   = (const float*)d_in[8];
  const float* b_ig   = (const float*)d_in[9];
  const float* W_og   = (const float*)d_in[10];
  const float* b_og   = (const float*)d_in[11];
  const float* W_fc   = (const float*)d_in[12];
  const float* b_fc   = (const float*)d_in[13];
  const float* W_act  = (const float*)d_in[14];
  const float* b_act  = (const float*)d_in[15];
  const float* W_out  = (const float*)d_in[16];
  const float* b_out  = (const float*)d_in[17];

  char* w = (char*)d_ws;
  bf16*  xn    = (bf16*)(w + OFF_XN);
  bf16*  gates = (bf16*)(w + OFF_GATES);   // f | ti | si | og, each SZ1 elems
  bf16*  xn2   = xn;                       // alias: xn dead after gemm<0>
  bf16*  ff    = gates;                    // alias: gates dead after scan_C
  bf16*  xrb   = (bf16*)(w + OFF_XR);
  bf16*  wg    = (bf16*)(w + OFF_WG);
  bf16*  wfn   = (bf16*)(w + OFF_WF);
  bf16*  wo    = (bf16*)(w + OFF_WO);
  float* scA   = (float*)(w + OFF_SCA);
  float* scB   = (float*)(w + OFF_SCB);
  float* scH   = (float*)(w + OFF_SCH);
  float* outp  = (float*)d_out;            // f32 output (reference dtype)
  float* hlast = outp + SZ1;

  const dim3 tb(32, 8);
  transpose_cvt<<<dim3(32, 32), tb, 0, stream>>>(W_f,  wg + 0 * 1048576, 1024, 1024);
  transpose_cvt<<<dim3(32, 32), tb, 0, stream>>>(W_i,  wg + 1 * 1048576, 1024, 1024);
  transpose_cvt<<<dim3(32, 32), tb, 0, stream>>>(W_ig, wg + 2 * 1048576, 1024, 1024);
  transpose_cvt<<<dim3(32, 32), tb, 0, stream>>>(W_og, wg + 3 * 1048576, 1024, 1024);
  transpose_ffn<<<dim3(256, 32), tb, 0, stream>>>(W_fc, W_act, wfn);
  transpose_cvt<<<dim3(32, 128), tb, 0, stream>>>(W_out, wo, 4096, 1024);

  rmsnorm_f32in<<<M, 256, 0, stream>>>(x, g_ql, xn);
  gemm_bt<0><<<dim3(32, 128), 256, 0, stream>>>(xn, wg, 1024, b_f, b_i, b_ig, b_og, nullptr, gates);
  scan_A<<<NCH * 512 / 256, 256, 0, stream>>>(gates, gates + SZ1, gates + 2 * SZ1, scA, scB);
  scan_Bk<<<16, 256, 0, stream>>>(scA, scB, hidden, scH);
  scan_C<<<NCH * 512 / 256, 256, 0, stream>>>(gates, gates + SZ1, gates + 2 * SZ1, gates + 3 * SZ1,
                                              x, scH, xrb, hlast);
  rmsnorm_b16in<<<M, 256, 0, stream>>>(xrb, g_ffn, xn2);
  gemm_bt<1><<<dim3(64, 128), 256, 0, stream>>>(xn2, wfn, 1024, b_fc, b_act, nullptr, nullptr, nullptr, ff);
  gemm_bt<2><<<dim3(8, 128), 256, 0, stream>>>(ff, wo, 4096, b_out, nullptr, nullptr, nullptr, xrb, (void*)outp);
}